// Round 1
// 2908.579 us; speedup vs baseline: 1.3356x; 1.3356x over previous
//
#include <hip/hip_runtime.h>
#include <hip/hip_bf16.h>

#define QD 1024
#define AD 26
#define BD 128
#define LD 1024
#define NWG 128          // 16 q-slices (64 q-out cols each) x 8 groups (bg x bhalf)
#define PSTR (8 * 32 * 64 * 8)   // ushorts per parity of packed alpha (256 KB)

typedef short bf16x8 __attribute__((ext_vector_type(8)));
typedef float f32x4 __attribute__((ext_vector_type(4)));

static __device__ __forceinline__ unsigned short f2bf(float f) {
    __hip_bfloat16 h = __float2bfloat16(f);
    return *reinterpret_cast<unsigned short*>(&h);
}

// Agent-scope relaxed 16B load (two 8B atomic loads -> served at device coherence pt).
static __device__ __forceinline__ bf16x8 load_a16(const unsigned short* p) {
    unsigned long long lo = __hip_atomic_load((const unsigned long long*)p,
                                              __ATOMIC_RELAXED, __HIP_MEMORY_SCOPE_AGENT);
    unsigned long long hi = __hip_atomic_load((const unsigned long long*)(p + 4),
                                              __ATOMIC_RELAXED, __HIP_MEMORY_SCOPE_AGENT);
    union { unsigned long long q[2]; bf16x8 v; } u;
    u.q[0] = lo; u.q[1] = hi;
    return u.v;
}

// Agent-scope relaxed 8B store (fire-and-forget; atomic => no tearing of a granule).
static __device__ __forceinline__ void store_a8(unsigned short* p, ushort4 v) {
    union { ushort4 s; unsigned long long q; } u; u.s = v;
    __hip_atomic_store((unsigned long long*)p, u.q,
                       __ATOMIC_RELAXED, __HIP_MEMORY_SCOPE_AGENT);
}

// Workgroup-scope LDS 16B load/store as 2x8B atomics: ds_read/write_b64, never
// hoisted out of the poll loop, no tearing within an 8B tagged granule.
static __device__ __forceinline__ bf16x8 lds_load16(const unsigned short* p) {
    unsigned long long lo = __hip_atomic_load((const unsigned long long*)p,
                                              __ATOMIC_RELAXED, __HIP_MEMORY_SCOPE_WORKGROUP);
    unsigned long long hi = __hip_atomic_load((const unsigned long long*)(p + 4),
                                              __ATOMIC_RELAXED, __HIP_MEMORY_SCOPE_WORKGROUP);
    union { unsigned long long q[2]; bf16x8 v; } u;
    u.q[0] = lo; u.q[1] = hi;
    return u.v;
}
static __device__ __forceinline__ void lds_store16(unsigned short* p, bf16x8 v) {
    union { bf16x8 v; unsigned long long q[2]; } u; u.v = v;
    __hip_atomic_store((unsigned long long*)p, u.q[0],
                       __ATOMIC_RELAXED, __HIP_MEMORY_SCOPE_WORKGROUP);
    __hip_atomic_store((unsigned long long*)(p + 4), u.q[1],
                       __ATOMIC_RELAXED, __HIP_MEMORY_SCOPE_WORKGROUP);
}

// Row-softmax of trans_logits [1024,1024] -> bf16 packed as A-fragments of T^T.
// A-frag layout (16x16x32): A[m = lane&15][k = quad*8 + j].
__global__ void softmax_pack_T(const float* __restrict__ tl, unsigned short* __restrict__ tf) {
    const int i = blockIdx.x;      // q_in
    const int tid = threadIdx.x;   // 256
    __shared__ float red[256];
    float v[4];
    float m = -1e30f;
    for (int c = 0; c < 4; ++c) { v[c] = tl[i * QD + tid + 256 * c]; m = fmaxf(m, v[c]); }
    red[tid] = m; __syncthreads();
    for (int s = 128; s > 0; s >>= 1) { if (tid < s) red[tid] = fmaxf(red[tid], red[tid + s]); __syncthreads(); }
    m = red[0]; __syncthreads();
    float sum = 0.f;
    for (int c = 0; c < 4; ++c) { v[c] = expf(v[c] - m); sum += v[c]; }
    red[tid] = sum; __syncthreads();
    for (int s = 128; s > 0; s >>= 1) { if (tid < s) red[tid] += red[tid + s]; __syncthreads(); }
    const float inv = 1.0f / red[0];
    const int kt = i >> 5, quad = (i >> 3) & 3, j = i & 7;
    for (int c = 0; c < 4; ++c) {
        const int q = tid + 256 * c;
        const int mt = q >> 4, col = q & 15;
        tf[(size_t)((mt * 32 + kt) * 64 + quad * 16 + col) * 8 + j] = f2bf(v[c] * inv);
    }
}

// Row-softmax of emis_logits [1024,26] -> bf16 A-fragments (M=q, K=a padded to 32).
__global__ void softmax_pack_B(const float* __restrict__ el, unsigned short* __restrict__ bmf) {
    const int q = blockIdx.x * blockDim.x + threadIdx.x;
    if (q >= QD) return;
    float v[AD];
    float m = -1e30f;
    for (int a = 0; a < AD; ++a) { v[a] = el[q * AD + a]; m = fmaxf(m, v[a]); }
    float sum = 0.f;
    for (int a = 0; a < AD; ++a) { v[a] = expf(v[a] - m); sum += v[a]; }
    const float inv = 1.0f / sum;
    const int mt = q >> 4, col = q & 15;
    for (int a = 0; a < 32; ++a) {
        const float val = (a < AD) ? v[a] * inv : 0.f;
        bmf[(size_t)(mt * 64 + (a >> 3) * 16 + col) * 8 + (a & 7)] = f2bf(val);
    }
}

__global__ void softmax_pi(const float* __restrict__ il, float* __restrict__ pi) {
    const int tid = threadIdx.x;   // 1024
    __shared__ float red[1024];
    const float v = il[tid];
    red[tid] = v; __syncthreads();
    for (int s = 512; s > 0; s >>= 1) { if (tid < s) red[tid] = fmaxf(red[tid], red[tid + s]); __syncthreads(); }
    const float m = red[0]; __syncthreads();
    const float e = expf(v - m);
    red[tid] = e; __syncthreads();
    for (int s = 512; s > 0; s >>= 1) { if (tid < s) red[tid] += red[tid + s]; __syncthreads(); }
    pi[tid] = e / red[0];
}

// Scan: 128 WGs x 256 threads = 16 q-slices (64 q-out columns) x 8 independent
// (batch-group x batch-half) domains. Same 512 waves as before, but the device-
// coherent exchange is now CHUNK-OWNED: the 32 B-frag chunks of each group's
// alpha are partitioned among the WG's 4 mtl-waves (8 chunks each). A wave
// validates ONLY its owned chunks from coherent memory (16 atomic loads/step vs
// 64), republishes the raw still-tagged granules into LDS, and the 3 sibling
// waves tag-poll LDS instead of MALL. Coherent read traffic: 16 MB -> 4 MB/step.
// LDS is parity-double-buffered (64 KB): slot t is overwritten by t+2 whose
// phase tag is opposite, so the sign-tag validation scheme carries over 1:1.
// Anti-overrun (global): a WG stores t+1 only after all its waves completed
// consume(t); consume(t) observes every other WG's store of t (8 chunks
// directly, 24 via siblings' LDS publishes, each of which implies that
// sibling's global validation), which transitively implies every wave of every
// WG finished consume(t-1), i.e. every coherent read of the t-1 slot is done.
// Anti-overrun (LDS): wave writes LDS slot (t+1) only after validating global
// own-chunks(t+1), which transitively implies its own siblings stored t (and
// thus finished reading LDS t-1 = same parity). No barriers, no flags, no
// drains anywhere in the loop.
__launch_bounds__(256, 1)
__global__ void hmm_scan(const float* __restrict__ inputs,
                         const unsigned short* __restrict__ tf,
                         const unsigned short* __restrict__ bmf,
                         const float* __restrict__ pi,
                         unsigned short* __restrict__ apack,  // 2 x PSTR ushorts (0xAA)
                         float* __restrict__ out) {
    const int tid   = threadIdx.x;
    const int mtl   = tid >> 6;                 // wave id = q-out subtile 0..3
    const int lane  = tid & 63;
    const int quad  = lane >> 4;
    const int col   = lane & 15;
    const int qs    = (int)blockIdx.x >> 3;     // 0..15: 64 q-out columns each
    const int grp   = (int)blockIdx.x & 7;      // bg*2 + bhalf
    const int b     = (grp >> 1) * 32 + (grp & 1) * 16 + col;  // this lane's batch
    const int qrow  = qs * 64 + mtl * 16 + quad * 4;

    // LDS re-share buffer: [parity][chunk][64 lanes x 8 ushorts]. Init to 0xAA
    // (sign bit set everywhere = invalid for both phases), one-time barrier.
    __shared__ unsigned short lbuf[2][32][512];
    {
        unsigned int* lp = (unsigned int*)lbuf;
        #pragma unroll
        for (int i = 0; i < 64; ++i) lp[tid + 256 * i] = 0xAAAAAAAAu;
        __syncthreads();
    }

    // Producer store target (ushort offset within a parity). Wave covers q-rows
    // [qs*64 + mtl*16, +16): chunk = qs*2 + (mtl>>1); within-chunk k' =
    // (mtl&1)*16 + quad*4 + r  ->  frag quad' = (mtl&1)*2 + (quad>>1), j =
    // (quad&1)*4 + r.
    const int lane_c = ((mtl & 1) * 2 + (quad >> 1)) * 16 + col;
    const size_t poff = (size_t)((grp * 32 + qs * 2 + (mtl >> 1)) * 64 + lane_c) * 8 + (quad & 1) * 4;
    // Consumer chunk base (ushort offset within a parity); chunk c at +c*512.
    const size_t coff = (size_t)(grp * 32) * 512 + (size_t)lane * 8;

    // All 32 T^T A-frags for this wave's 16 q-out rows into registers.
    bf16x8 tfr[32];
    {
        const bf16x8* tsrc = (const bf16x8*)tf + (size_t)(qs * 4 + mtl) * 32 * 64 + lane;
        #pragma unroll
        for (int kt = 0; kt < 32; ++kt) tfr[kt] = tsrc[(size_t)kt * 64];
    }
    const bf16x8 bmA = *(const bf16x8*)&bmf[(size_t)((qs * 4 + mtl) * 64 + lane) * 8];
    float pr[4];
    #pragma unroll
    for (int r = 0; r < 4; ++r) pr[r] = pi[qrow + r];

    bf16x8 ones;
    #pragma unroll
    for (int i = 0; i < 8; ++i) ones[i] = (short)0x3F80;

    const f32x4 fz = {0.f, 0.f, 0.f, 0.f};
    const unsigned M = 0x80008000u;
    float ll = 0.f;

    // Emission(0): direct register loads.
    f32x4 e;
    {
        bf16x8 xb;
        #pragma unroll
        for (int j = 0; j < 8; ++j) {
            const int a = quad * 8 + j;
            const float v = (a < AD) ? inputs[(size_t)b * LD * AD + a] : 0.f;
            xb[j] = (short)f2bf(v);
        }
        e = __builtin_amdgcn_mfma_f32_16x16x32_bf16(bmA, xb, fz, 0, 0, 0);
    }

    f32x4 acc = fz, on = fz;

    for (int t = 0; t < LD; ++t) {
        float v0[4];
        if (t == 0) {
            #pragma unroll
            for (int r = 0; r < 4; ++r) v0[r] = pr[r] * e[r];
        } else {
            const float i0 = 1.f / on[0];
            #pragma unroll
            for (int r = 0; r < 4; ++r) v0[r] = acc[r] * e[r] * i0;
        }
        // Tag elements 2,3 with phase(t); fire-and-forget atomic store.
        const unsigned short tagbit = (unsigned short)(((t >> 1) & 1) << 15);
        ushort4 s0;
        s0.x = f2bf(v0[0]); s0.y = f2bf(v0[1]);
        s0.z = (unsigned short)(f2bf(v0[2]) | tagbit);
        s0.w = (unsigned short)(f2bf(v0[3]) | tagbit);
        store_a8(apack + (size_t)(t & 1) * PSTR + poff, s0);

        if (qs == 0 && mtl == 0 && t > 0) ll += logf(on[0]);  // on[0] == c_{t-1}[batch]

        if (t + 1 < LD) {
            // Emission(t+1) while our store is in flight.
            bf16x8 xb;
            #pragma unroll
            for (int j = 0; j < 8; ++j) {
                const int a = quad * 8 + j;
                const float v = (a < AD)
                    ? inputs[((size_t)b * LD + (t + 1)) * AD + a] : 0.f;
                xb[j] = (short)f2bf(v);
            }
            e = __builtin_amdgcn_mfma_f32_16x16x32_bf16(bmA, xb, fz, 0, 0, 0);

            const unsigned short* cp = apack + (size_t)(t & 1) * PSTR + coff;
            const unsigned E = ((t >> 1) & 1) ? M : 0u;

            // (1) Validate the 8 OWNED chunks from device-coherent memory.
            bf16x8 bufr[8];
            unsigned bad;
            do {
                #pragma unroll
                for (int k = 0; k < 8; ++k)
                    bufr[k] = load_a16(cp + (size_t)(mtl * 8 + k) * 512);
                bad = 0u;
                #pragma unroll
                for (int k = 0; k < 8; ++k) {
                    union { bf16x8 v; uint4 u; } w; w.v = bufr[k];
                    bad |= (w.u.x | w.u.z | (w.u.y ^ E) | (w.u.w ^ E)) & M;
                }
            } while (__ballot(bad == 0u) != ~0ULL);

            // (2) Republish raw (still-tagged) chunks into LDS for siblings.
            #pragma unroll
            for (int k = 0; k < 8; ++k)
                lds_store16(&lbuf[t & 1][mtl * 8 + k][lane * 8], bufr[k]);

            // (3) Consume all 32 chunks in fixed order (tfr indices are
            // compile-time): own group from registers, others tag-polled LDS.
            acc = fz; on = fz;
            #pragma unroll
            for (int g = 0; g < 4; ++g) {
                if (g == mtl) {
                    #pragma unroll
                    for (int k = 0; k < 8; ++k) {
                        union { bf16x8 v; uint4 u; } w; w.v = bufr[k];
                        w.u.x &= ~M; w.u.y &= ~M; w.u.z &= ~M; w.u.w &= ~M;
                        acc = __builtin_amdgcn_mfma_f32_16x16x32_bf16(tfr[g * 8 + k], w.v, acc, 0, 0, 0);
                        on  = __builtin_amdgcn_mfma_f32_16x16x32_bf16(ones, w.v, on, 0, 0, 0);
                    }
                } else {
                    bf16x8 lb[8];
                    do {
                        #pragma unroll
                        for (int k = 0; k < 8; ++k)
                            lb[k] = lds_load16(&lbuf[t & 1][g * 8 + k][lane * 8]);
                        bad = 0u;
                        #pragma unroll
                        for (int k = 0; k < 8; ++k) {
                            union { bf16x8 v; uint4 u; } w; w.v = lb[k];
                            bad |= (w.u.x | w.u.z | (w.u.y ^ E) | (w.u.w ^ E)) & M;
                        }
                    } while (__ballot(bad == 0u) != ~0ULL);
                    #pragma unroll
                    for (int k = 0; k < 8; ++k) {
                        union { bf16x8 v; uint4 u; } w; w.v = lb[k];
                        w.u.x &= ~M; w.u.y &= ~M; w.u.z &= ~M; w.u.w &= ~M;
                        acc = __builtin_amdgcn_mfma_f32_16x16x32_bf16(tfr[g * 8 + k], w.v, acc, 0, 0, 0);
                        on  = __builtin_amdgcn_mfma_f32_16x16x32_bf16(ones, w.v, on, 0, 0, 0);
                    }
                }
            }
        }
    }

    // Final normalizer c_{L-1}; only qs==0 / mtl==0 waves produce output.
    // Reads all 32 chunks straight from coherent memory (one-time, no LDS).
    if (qs == 0 && mtl == 0) {
        const unsigned short* cp = apack + (size_t)((LD - 1) & 1) * PSTR + coff;
        const unsigned E = (((LD - 1) >> 1) & 1) ? M : 0u;
        f32x4 f0 = fz;
        #pragma unroll
        for (int h = 0; h < 2; ++h) {
            bf16x8 bufr[16];
            unsigned bad;
            do {
                #pragma unroll
                for (int k = 0; k < 16; ++k)
                    bufr[k] = load_a16(cp + (size_t)(h * 16 + k) * 512);
                bad = 0u;
                #pragma unroll
                for (int k = 0; k < 16; ++k) {
                    union { bf16x8 v; uint4 u; } w; w.v = bufr[k];
                    bad |= (w.u.x | w.u.z | (w.u.y ^ E) | (w.u.w ^ E)) & M;
                }
            } while (__ballot(bad == 0u) != ~0ULL);
            #pragma unroll
            for (int k = 0; k < 16; ++k) {
                union { bf16x8 v; uint4 u; } w; w.v = bufr[k];
                w.u.x &= ~M; w.u.y &= ~M; w.u.z &= ~M; w.u.w &= ~M;
                f0 = __builtin_amdgcn_mfma_f32_16x16x32_bf16(ones, w.v, f0, 0, 0, 0);
            }
        }
        if (quad == 0) out[b] = ll + logf(f0[0]);
    }
}

extern "C" void kernel_launch(void* const* d_in, const int* in_sizes, int n_in,
                              void* d_out, int out_size, void* d_ws, size_t ws_size,
                              hipStream_t stream) {
    const float* inputs       = (const float*)d_in[0];
    const float* init_logits  = (const float*)d_in[1];
    const float* trans_logits = (const float*)d_in[2];
    const float* emis_logits  = (const float*)d_in[3];
    float* out = (float*)d_out;

    unsigned short* tf    = (unsigned short*)d_ws;                 // 2 MB
    unsigned short* bmf   = tf + (size_t)QD * QD;                  // 64 KB
    float* pi             = (float*)(bmf + (size_t)QD * 32);       // 4 KB
    unsigned short* apack = (unsigned short*)(pi + QD);            // 512 KB

    // Self-contained tag init: 0xAA bytes => every bf16 sign bit set => invalid
    // for BOTH phases.
    hipMemsetAsync(apack, 0xAA, (size_t)2 * PSTR * sizeof(unsigned short), stream);

    softmax_pack_T<<<1024, 256, 0, stream>>>(trans_logits, tf);
    softmax_pack_B<<<4, 256, 0, stream>>>(emis_logits, bmf);
    softmax_pi<<<1, 1024, 0, stream>>>(init_logits, pi);

    // Plain launch: 128 blocks co-resident on 256 CUs by dispatch.
    hmm_scan<<<NWG, 256, 0, stream>>>(inputs, tf, bmf, pi, apack, out);
}